// Round 1
// 213.492 us; speedup vs baseline: 1.0144x; 1.0144x over previous
//
#include <hip/hip_runtime.h>
#include <stdint.h>

#define F_IN 65536
#define NN 100
#define CO 60
#define G_SPLIT 128
#define KC (F_IN/G_SPLIT)   // 512
#define BK 64
#define NIT (KC/BK)         // 8
#define AST 72              // A LDS row stride in shorts (144 B: 16B-aligned, 2-way bank alias = free)
#define BTILE (BK*CO)       // 3840 floats / shorts per B tile
#define BQ (BTILE/4)        // 960 float4 per B tile

typedef short v8s __attribute__((ext_vector_type(8)));
typedef float v4f __attribute__((ext_vector_type(4)));

__device__ __forceinline__ unsigned int f2bf(float x){
  unsigned int u = __float_as_uint(x);
  u += 0x7fffu + ((u>>16)&1u);      // round-to-nearest-even
  return u>>16;
}

__device__ __forceinline__ v4f mfma16(v8s a, v8s b, v4f c){
  return __builtin_amdgcn_mfma_f32_16x16x32_bf16(a,b,c,0,0,0);
}

// ---------------------------------------------------------------------------
// K1: split-K GEMM.  grid = 768 1-D blocks.  Decode co-locates the 6 g-blocks
// (a0,a1,a2,c0,c1,c2) of each k-slice s on ONE XCD (consecutive slots, bid%8
// round-robin) so 5/6 of the X reads hit that XCD's L2.
// B path: W tile (64x60 f32, contiguous 15360 B) loaded as flat float4
// (coalesced), staged to LDS as bf16 (contiguous uint2 writes), fragments
// gathered with ds_read_u16 (stride 60 shorts, <=4-way alias).
// A path: unchanged (float4 -> bf16 -> LDS, 7 m-tiles, M padded 100->112).
// Software-pipelined 1-deep; double-buffered LDS; one barrier/iter.
// ---------------------------------------------------------------------------
__global__ __launch_bounds__(256,3)
void k_gemm(const float* __restrict__ x, const float* __restrict__ aw,
            const float* __restrict__ cw, float* __restrict__ dst, int partial){
  const int bid  = blockIdx.x;
  const int xcd  = bid & 7, slot = bid >> 3;    // 96 slots per XCD
  const int sdiv = slot / 6;
  const int s    = xcd*16 + sdiv;               // k-slice
  const int g    = slot - sdiv*6;               // matrix
  const int k0   = s*KC;
  const int tid  = threadIdx.x;
  const int wave = tid>>6, lane = tid&63, quad = lane>>4, nl = lane&15;
  const int c0   = wave*16;
  const int ccl  = min(c0+nl, CO-1);            // clamp pad cols; discarded at store

  const float* W    = (g<3) ? (aw + (size_t)g*F_IN*CO) : (cw + (size_t)(g-3)*F_IN*CO);
  const float* bsrc = W + (size_t)k0*CO;        // tile base; +it*BK*CO per iter (16B-aligned: 240B rows)

  __shared__ __align__(16) unsigned short Al[2][112*AST];
  __shared__ __align__(16) unsigned short Bl[2][BTILE];

  // staging geometry A: thread covers 7 (row,q) cells; row=lin>>4, q=lin&15
  float4 ra[7];
  float4 rbv[4];
  #pragma unroll
  for(int p=0;p<7;++p){
    int lin = p*256 + tid, row = lin>>4, q = lin&15;
    int rcl = min(row, NN-1);
    ra[p] = *(const float4*)(x + (size_t)rcl*F_IN + k0 + q*4);
  }
  #pragma unroll
  for(int p=0;p<4;++p){
    int f = min(p*256 + tid, BQ-1);             // clamp: dup loads, writes guarded
    rbv[p] = *(const float4*)(bsrc + f*4);
  }

  v4f acc[7];
  #pragma unroll
  for(int i=0;i<7;++i){ v4f z={0.f,0.f,0.f,0.f}; acc[i]=z; }

  for(int it=0; it<NIT; ++it){
    unsigned short* buf  = Al[it&1];
    unsigned short* bbuf = Bl[it&1];
    // --- write prefetched A tile (bf16) ---
    #pragma unroll
    for(int p=0;p<7;++p){
      int lin = p*256 + tid, row = lin>>4, q = lin&15;
      uint2 w;
      w.x = f2bf(ra[p].x) | (f2bf(ra[p].y)<<16);
      w.y = f2bf(ra[p].z) | (f2bf(ra[p].w)<<16);
      *(uint2*)(buf + row*AST + q*4) = w;
    }
    // --- write prefetched B tile (bf16, flat row-major [64][60]) ---
    #pragma unroll
    for(int p=0;p<4;++p){
      int f = p*256 + tid;
      if(f < BQ){
        uint2 w;
        w.x = f2bf(rbv[p].x) | (f2bf(rbv[p].y)<<16);
        w.y = f2bf(rbv[p].z) | (f2bf(rbv[p].w)<<16);
        *(uint2*)(bbuf + f*4) = w;
      }
    }
    __syncthreads();
    // --- kick next iteration's global loads (in flight behind MFMA) ---
    if(it+1 < NIT){
      const int kb = k0 + (it+1)*BK;
      #pragma unroll
      for(int p=0;p<7;++p){
        int lin = p*256 + tid, row = lin>>4, q = lin&15;
        int rcl = min(row, NN-1);
        ra[p] = *(const float4*)(x + (size_t)rcl*F_IN + kb + q*4);
      }
      const float* bs2 = bsrc + (size_t)(it+1)*BK*CO;
      #pragma unroll
      for(int p=0;p<4;++p){
        int f = min(p*256 + tid, BQ-1);
        rbv[p] = *(const float4*)(bs2 + f*4);
      }
    }
    // --- B fragments from LDS (16 x ds_read_u16, stride 60 shorts) ---
    const unsigned short* bb = bbuf + quad*8*CO + ccl;
    v8s fB0, fB1;
    #pragma unroll
    for(int j=0;j<8;++j){
      fB0[j] = (short)bb[j*CO];
      fB1[j] = (short)bb[32*CO + j*CO];
    }
    // --- MFMA over 7 m-tiles ---
    #pragma unroll
    for(int mt=0; mt<7; ++mt){
      const unsigned short* arow = buf + (mt*16+nl)*AST + quad*8;
      v8s a0 = *(const v8s*)(arow);
      v8s a1 = *(const v8s*)(arow+32);
      acc[mt] = mfma16(a0, fB0, acc[mt]);
      acc[mt] = mfma16(a1, fB1, acc[mt]);
    }
  }

  // --- epilogue.  C/D layout: col=lane&15, row=quad*4+i ---
  const int c = c0 + nl;
  if(c < CO){
    if(partial){
      float* pd = dst + ((size_t)g*G_SPLIT + s)*(NN*CO);
      #pragma unroll
      for(int mt=0;mt<7;++mt){
        #pragma unroll
        for(int i=0;i<4;++i){
          int m = mt*16 + quad*4 + i;
          if(m < NN) pd[m*CO + c] = acc[mt][i];
        }
      }
    } else {
      float* pd = dst + (size_t)g*(NN*CO);
      #pragma unroll
      for(int mt=0;mt<7;++mt){
        #pragma unroll
        for(int i=0;i<4;++i){
          int m = mt*16 + quad*4 + i;
          if(m < NN) atomicAdd(pd + m*CO + c, acc[mt][i]);
        }
      }
    }
  }
}

// ---------------------------------------------------------------------------
// K1b: split-K reduce.  grid=(141); single-writer (no atomics, no Y memset):
// thread o sums all 128 slices (coalesced 256B/wave loads, stride 6000 floats).
// ---------------------------------------------------------------------------
__global__ void k_reduce(const float* __restrict__ P, float* __restrict__ Y){
  int o = blockIdx.x*256 + threadIdx.x;
  if(o >= 6*NN*CO) return;
  int gg = o/(NN*CO), r = o - gg*(NN*CO);
  const float* p = P + (size_t)gg*G_SPLIT*(NN*CO) + r;
  float a0=0.f,a1=0.f,a2=0.f,a3=0.f;
  #pragma unroll 4
  for(int s4=0;s4<G_SPLIT;s4+=4){
    a0 += p[(size_t)(s4  )*(NN*CO)];
    a1 += p[(size_t)(s4+1)*(NN*CO)];
    a2 += p[(size_t)(s4+2)*(NN*CO)];
    a3 += p[(size_t)(s4+3)*(NN*CO)];
  }
  Y[o] = (a0+a1)+(a2+a3);
}

// ---------------------------------------------------------------------------
// K2: cheb combine.  out = Y0 - Y2 + L@(Y1 + 2*L@Y2) + b, then tanh.
// One block per (net, output column c).  L (100x100) rebuilt in LDS per block.
// Block 0 also zeroes out[0..100] (replaces host memset; k_fc is stream-later).
// ---------------------------------------------------------------------------
__global__ void k_cheb(const float* __restrict__ Y, const int* __restrict__ ei,
                       const float* __restrict__ ab, const float* __restrict__ cb,
                       float* __restrict__ emb, float* __restrict__ out){
  const int net = blockIdx.x / CO;
  const int c   = blockIdx.x % CO;
  const int t   = threadIdx.x;       // 128
  __shared__ float L[NN][NN+1];      // stride 101: 2-way bank alias only
  __shared__ float dis[NN];
  __shared__ int   deg[NN];
  __shared__ float y0[NN], y1[NN], y2[NN], zu[NN];

  if(blockIdx.x==0 && t<101) out[t] = 0.f;

  for(int i=t;i<NN*(NN+1);i+=128) ((float*)L)[i]=0.f;
  if(t<NN) deg[t]=0;
  __syncthreads();
  for(int e=t;e<2000;e+=128) atomicAdd(&deg[ei[e]],1);
  __syncthreads();
  if(t<NN) dis[t] = deg[t]>0 ? rsqrtf((float)deg[t]) : 0.f;
  __syncthreads();
  for(int e=t;e<2000;e+=128){
    int s = ei[e], d = ei[2000+e];
    atomicAdd(&L[d][s], -dis[s]*dis[d]);
  }
  if(t<NN){
    const float* yb = Y + (size_t)net*3*NN*CO + t*CO + c;
    y0[t]=yb[0]; y1[t]=yb[NN*CO]; y2[t]=yb[2*NN*CO];
  }
  __syncthreads();
  if(t<NN){
    float s=0.f;
    #pragma unroll 4
    for(int j=0;j<NN;++j) s += L[t][j]*y2[j];
    zu[t] = y1[t] + 2.f*s;
  }
  __syncthreads();
  if(t<NN){
    float s=0.f;
    #pragma unroll 4
    for(int j=0;j<NN;++j) s += L[t][j]*zu[j];
    float b = (net==0) ? ab[c] : cb[c];
    emb[net*NN*CO + t*CO + c] = tanhf(y0[t] - y2[t] + s + b);
  }
}

// ---------------------------------------------------------------------------
// K3: final FC.  out zeroed by k_cheb block 0.  Blocks 0..24: coalesced logits
// partials (lane = output column j, 240 i-rows per block), atomicAdd.
// Block 25: value dot + biases + scalar extras.
// ---------------------------------------------------------------------------
#define FCB 25
__global__ void k_fc(const float* __restrict__ emb, const float* __restrict__ afw,
                     const float* __restrict__ afb, const float* __restrict__ cfw,
                     const float* __restrict__ cfb, const float* __restrict__ s0,
                     const float* __restrict__ s1, const float* __restrict__ s2,
                     float* __restrict__ out){
  const int b = blockIdx.x;
  const int t = threadIdx.x;         // 256
  if(b < FCB){
    const int jj = t & 127, half = t >> 7;
    if(jj < 100){
      const int i0 = b*240 + half*120;
      const float* w = afw + (size_t)i0*100 + jj;
      const float* e = emb + i0;
      float p = 0.f;
      #pragma unroll 4
      for(int i=0;i<120;++i) p += e[i]*w[(size_t)i*100];
      atomicAdd(&out[jj], p);
    }
  } else {
    float p = 0.f;
    const float* e = emb + 6000;
    for(int i=t;i<6000;i+=256) p += e[i]*cfw[i];
    #pragma unroll
    for(int o=32;o>0;o>>=1) p += __shfl_down(p,o,64);
    __shared__ float red[4];
    if((t&63)==0) red[t>>6]=p;
    __syncthreads();
    if(t==0){
      float tot = red[0]+red[1]+red[2]+red[3];
      out[100] = tot + s0[0]*cfw[6000] + s1[0]*cfw[6001] + s2[0]*cfw[6002] + cfb[0];
    }
    if(t<100){
      atomicAdd(&out[t], afb[t] + s0[0]*afw[600000+t] + s1[0]*afw[600100+t] + s2[0]*afw[600200+t]);
    }
  }
}

extern "C" void kernel_launch(void* const* d_in, const int* in_sizes, int n_in,
                              void* d_out, int out_size, void* d_ws, size_t ws_size,
                              hipStream_t stream){
  const float* x   = (const float*)d_in[0];
  const int*   ei  = (const int*)d_in[1];
  const float* s0  = (const float*)d_in[2];
  const float* s1  = (const float*)d_in[3];
  const float* s2  = (const float*)d_in[4];
  const float* aw  = (const float*)d_in[5];
  const float* ab  = (const float*)d_in[6];
  const float* cw  = (const float*)d_in[7];
  const float* cb  = (const float*)d_in[8];
  const float* afw = (const float*)d_in[9];
  const float* afb = (const float*)d_in[10];
  const float* cfw = (const float*)d_in[11];
  const float* cfb = (const float*)d_in[12];
  float* out = (float*)d_out;

  float* Y   = (float*)d_ws;                       // [6][6000] reduced GEMM outputs
  float* emb = Y + 6*NN*CO;                        // [2][6000] tanh embeddings
  float* P   = emb + 2*NN*CO;                      // [6][G_SPLIT][6000] split-K partials
  const size_t need = (size_t)(6*NN*CO + 2*NN*CO + (size_t)6*G_SPLIT*NN*CO)*sizeof(float);
  const int partial = (ws_size >= need) ? 1 : 0;

  if(partial){
    k_gemm<<<dim3(G_SPLIT*6), 256, 0, stream>>>(x, aw, cw, P, 1);
    k_reduce<<<dim3((6*NN*CO+255)/256), 256, 0, stream>>>(P, Y);
  } else {
    hipMemsetAsync(Y, 0, 6*NN*CO*sizeof(float), stream);
    k_gemm<<<dim3(G_SPLIT*6), 256, 0, stream>>>(x, aw, cw, Y, 0);
  }
  k_cheb<<<120, 128, 0, stream>>>(Y, ei, ab, cb, emb, out);
  k_fc<<<FCB+1, 256, 0, stream>>>(emb, afw, afb, cfw, cfb, s0, s1, s2, out);
}

// Round 3
// 209.103 us; speedup vs baseline: 1.0357x; 1.0210x over previous
//
#include <hip/hip_runtime.h>
#include <stdint.h>

#define F_IN 65536
#define NN 100
#define CO 60
#define G2 256              // split-K slices
#define KC (F_IN/G2)        // 256 k per slice
#define BK 64
#define NIT (KC/BK)         // 4
#define AST 72              // A LDS row stride in shorts (144 B: 16B-aligned, bank-rotating)
#define BTILE (BK*CO)       // 3840 shorts per B tile (one matrix)
#define BQ3 (3*BTILE/4)     // 2880 float4 per 3-matrix B stage

typedef short v8s __attribute__((ext_vector_type(8)));
typedef float v4f __attribute__((ext_vector_type(4)));

__device__ __forceinline__ unsigned int f2bf(float x){
  unsigned int u = __float_as_uint(x);
  u += 0x7fffu + ((u>>16)&1u);      // round-to-nearest-even
  return u>>16;
}

__device__ __forceinline__ v4f mfma16(v8s a, v8s b, v4f c){
  return __builtin_amdgcn_mfma_f32_16x16x32_bf16(a,b,c,0,0,0);
}

// ---------------------------------------------------------------------------
// K1: split-K GEMM, 3 weight matrices per block (they share the A tile = X).
// grid = 512: (s in [0,256)) x (net in {0,1}).  XCD decode: the 2 net-blocks
// of a slice sit on one XCD (X slice L2-shared); per-XCD X footprint 3.3 MB
// fits the 4 MB L2.
// Per iter/wave: 42 MFMA vs 14 before -> 3x compute density per A byte.
// Wave w owns output col-tile c0=w*16 for all 3 g and all 7 m-tiles
// (acc[3][7] = 84 VGPR).  1-deep software pipeline, double-buffered LDS.
// ---------------------------------------------------------------------------
__global__ __launch_bounds__(256,2)
void k_gemm(const float* __restrict__ x, const float* __restrict__ aw,
            const float* __restrict__ cw, float* __restrict__ dst, int partial){
  const int bid  = blockIdx.x;
  const int xcd  = bid & 7, slot = bid >> 3;   // 64 slots/XCD
  const int net  = slot & 1;
  const int s    = xcd*32 + (slot >> 1);       // k-slice
  const int k0   = s*KC;
  const int tid  = threadIdx.x;
  const int wave = tid>>6, lane = tid&63, quad = lane>>4, nl = lane&15;
  const int c0   = wave*16;
  const int ccl  = min(c0+nl, CO-1);           // clamp pad cols; masked at store

  const float* Wn = net ? cw : aw;             // [3][F_IN][CO]

  __shared__ __align__(16) unsigned short Al[2][112*AST];   // 32.25 KB
  __shared__ __align__(16) unsigned short Bl[2][3*BTILE];   // 46.08 KB

  // ---- per-thread staging geometry ----
  // A: 7 cells, lin = p*256+tid in [0,1792): row=lin>>4, q=lin&15 (float4)
  // B: 12 cells, lin = p*256+tid in [0,3072), guard <2880: g=lin/960, f=lin%960
  unsigned int boff[12];                       // byte offset into Wn (32-bit ok: <95MB)
  #pragma unroll
  for(int p=0;p<12;++p){
    int li = min(p*256 + tid, BQ3-1);
    int gp = li/960, fp = li - gp*960;
    boff[p] = (unsigned int)((size_t)gp*F_IN*CO + (size_t)fp*4)*4u;
  }
  const char* bbase0 = (const char*)(Wn + (size_t)k0*CO);

  float4 ra[7];
  float4 rbv[12];
  #pragma unroll
  for(int p=0;p<7;++p){
    int lin = p*256 + tid, row = lin>>4, q = lin&15;
    int rcl = min(row, NN-1);
    ra[p] = *(const float4*)(x + (size_t)rcl*F_IN + k0 + q*4);
  }
  #pragma unroll
  for(int p=0;p<12;++p) rbv[p] = *(const float4*)(bbase0 + boff[p]);

  v4f acc[3][7];
  #pragma unroll
  for(int g=0;g<3;++g)
    #pragma unroll
    for(int i=0;i<7;++i){ v4f z={0.f,0.f,0.f,0.f}; acc[g][i]=z; }

  for(int it=0; it<NIT; ++it){
    unsigned short* buf  = Al[it&1];
    unsigned short* bbuf = Bl[it&1];
    // --- write prefetched A tile (bf16) ---
    #pragma unroll
    for(int p=0;p<7;++p){
      int lin = p*256 + tid, row = lin>>4, q = lin&15;
      uint2 w;
      w.x = f2bf(ra[p].x) | (f2bf(ra[p].y)<<16);
      w.y = f2bf(ra[p].z) | (f2bf(ra[p].w)<<16);
      *(uint2*)(buf + row*AST + q*4) = w;
    }
    // --- write prefetched B tiles (bf16, flat [3][64][60]) ---
    #pragma unroll
    for(int p=0;p<12;++p){
      int lin = p*256 + tid;
      if(lin < BQ3){
        uint2 w;
        w.x = f2bf(rbv[p].x) | (f2bf(rbv[p].y)<<16);
        w.y = f2bf(rbv[p].z) | (f2bf(rbv[p].w)<<16);
        *(uint2*)(bbuf + lin*4) = w;
      }
    }
    __syncthreads();
    // --- kick next iteration's global loads (in flight behind MFMA) ---
    if(it+1 < NIT){
      const int kb = k0 + (it+1)*BK;
      #pragma unroll
      for(int p=0;p<7;++p){
        int lin = p*256 + tid, row = lin>>4, q = lin&15;
        int rcl = min(row, NN-1);
        ra[p] = *(const float4*)(x + (size_t)rcl*F_IN + kb + q*4);
      }
      const char* bb2 = bbase0 + (size_t)(it+1)*BK*CO*4;
      #pragma unroll
      for(int p=0;p<12;++p) rbv[p] = *(const float4*)(bb2 + boff[p]);
    }
    // --- B fragments from LDS (3 g x 16 ds_read_u16, stride 60 shorts) ---
    v8s fB0[3], fB1[3];
    #pragma unroll
    for(int g=0;g<3;++g){
      const unsigned short* bb = bbuf + g*BTILE + quad*8*CO + ccl;
      #pragma unroll
      for(int j=0;j<8;++j){
        fB0[g][j] = (short)bb[j*CO];
        fB1[g][j] = (short)bb[32*CO + j*CO];
      }
    }
    // --- MFMA: A frag read once, used by all 3 matrices ---
    #pragma unroll
    for(int mt=0; mt<7; ++mt){
      const unsigned short* arow = buf + (mt*16+nl)*AST + quad*8;
      v8s a0 = *(const v8s*)(arow);
      v8s a1 = *(const v8s*)(arow+32);
      #pragma unroll
      for(int g=0;g<3;++g){
        acc[g][mt] = mfma16(a0, fB0[g], acc[g][mt]);
        acc[g][mt] = mfma16(a1, fB1[g], acc[g][mt]);
      }
    }
  }

  // --- epilogue.  C/D layout: col=lane&15, row=quad*4+i ---
  const int c = c0 + nl;
  if(c < CO){
    #pragma unroll
    for(int g=0;g<3;++g){
      if(partial){
        float* pd = dst + ((size_t)(net*3+g)*G2 + s)*(NN*CO);
        #pragma unroll
        for(int mt=0;mt<7;++mt){
          #pragma unroll
          for(int i=0;i<4;++i){
            int m = mt*16 + quad*4 + i;
            if(m < NN) pd[m*CO + c] = acc[g][mt][i];
          }
        }
      } else {
        float* pd = dst + (size_t)(net*3+g)*(NN*CO);
        #pragma unroll
        for(int mt=0;mt<7;++mt){
          #pragma unroll
          for(int i=0;i<4;++i){
            int m = mt*16 + quad*4 + i;
            if(m < NN) atomicAdd(pd + m*CO + c, acc[g][mt][i]);
          }
        }
      }
    }
  }
}

// ---------------------------------------------------------------------------
// K1b: split-K reduce.  grid=(141,8): block (b,sg) sums 32 slices of P into Y
// via one atomicAdd (Y zeroed by memset).  8 s-groups -> 8x the TLP of a
// single-writer walk; per-thread chain is 32 strided loads (4-unrolled).
// ---------------------------------------------------------------------------
__global__ void k_reduce(const float* __restrict__ P, float* __restrict__ Y){
  int o = blockIdx.x*256 + threadIdx.x;
  if(o >= 6*NN*CO) return;
  int gg = o/(NN*CO), r = o - gg*(NN*CO);
  const float* p = P + (size_t)gg*G2*(NN*CO) + (size_t)blockIdx.y*32*(NN*CO) + r;
  float a0=0.f,a1=0.f,a2=0.f,a3=0.f;
  #pragma unroll 2
  for(int s4=0;s4<32;s4+=4){
    a0 += p[(size_t)(s4  )*(NN*CO)];
    a1 += p[(size_t)(s4+1)*(NN*CO)];
    a2 += p[(size_t)(s4+2)*(NN*CO)];
    a3 += p[(size_t)(s4+3)*(NN*CO)];
  }
  atomicAdd(&Y[o], (a0+a1)+(a2+a3));
}

// ---------------------------------------------------------------------------
// K2: cheb combine.  out = Y0 - Y2 + L@(Y1 + 2*L@Y2) + b, then tanh.
// One block per (net, output column c).  L (100x100) rebuilt in LDS per block.
// Block 0 also zeroes out[0..100].
// ---------------------------------------------------------------------------
__global__ void k_cheb(const float* __restrict__ Y, const int* __restrict__ ei,
                       const float* __restrict__ ab, const float* __restrict__ cb,
                       float* __restrict__ emb, float* __restrict__ out){
  const int net = blockIdx.x / CO;
  const int c   = blockIdx.x % CO;
  const int t   = threadIdx.x;       // 128
  __shared__ float L[NN][NN+1];      // stride 101: 2-way bank alias only
  __shared__ float dis[NN];
  __shared__ int   deg[NN];
  __shared__ float y0[NN], y1[NN], y2[NN], zu[NN];

  if(blockIdx.x==0 && t<101) out[t] = 0.f;

  for(int i=t;i<NN*(NN+1);i+=128) ((float*)L)[i]=0.f;
  if(t<NN) deg[t]=0;
  __syncthreads();
  for(int e=t;e<2000;e+=128) atomicAdd(&deg[ei[e]],1);
  __syncthreads();
  if(t<NN) dis[t] = deg[t]>0 ? rsqrtf((float)deg[t]) : 0.f;
  __syncthreads();
  for(int e=t;e<2000;e+=128){
    int s = ei[e], d = ei[2000+e];
    atomicAdd(&L[d][s], -dis[s]*dis[d]);
  }
  if(t<NN){
    const float* yb = Y + (size_t)net*3*NN*CO + t*CO + c;
    y0[t]=yb[0]; y1[t]=yb[NN*CO]; y2[t]=yb[2*NN*CO];
  }
  __syncthreads();
  if(t<NN){
    float s=0.f;
    #pragma unroll 4
    for(int j=0;j<NN;++j) s += L[t][j]*y2[j];
    zu[t] = y1[t] + 2.f*s;
  }
  __syncthreads();
  if(t<NN){
    float s=0.f;
    #pragma unroll 4
    for(int j=0;j<NN;++j) s += L[t][j]*zu[j];
    float b = (net==0) ? ab[c] : cb[c];
    emb[net*NN*CO + t*CO + c] = tanhf(y0[t] - y2[t] + s + b);
  }
}

// ---------------------------------------------------------------------------
// K3: final FC.  out zeroed by k_cheb block 0.  Blocks 0..49: logits partials
// (lane = output column j, 120 i-rows per block, 4 independent accumulators),
// atomicAdd.  Block 50: value dot + biases + scalar extras.
// ---------------------------------------------------------------------------
#define FCB 50
__global__ void k_fc(const float* __restrict__ emb, const float* __restrict__ afw,
                     const float* __restrict__ afb, const float* __restrict__ cfw,
                     const float* __restrict__ cfb, const float* __restrict__ s0,
                     const float* __restrict__ s1, const float* __restrict__ s2,
                     float* __restrict__ out){
  const int b = blockIdx.x;
  const int t = threadIdx.x;         // 256
  if(b < FCB){
    const int jj = t & 127, half = t >> 7;
    if(jj < 100){
      const int i0 = b*120 + half*60;
      const float* w = afw + (size_t)i0*100 + jj;
      const float* e = emb + i0;
      float p0=0.f,p1=0.f,p2=0.f,p3=0.f;
      #pragma unroll 3
      for(int i=0;i<60;i+=4){
        p0 += e[i  ]*w[(size_t)(i  )*100];
        p1 += e[i+1]*w[(size_t)(i+1)*100];
        p2 += e[i+2]*w[(size_t)(i+2)*100];
        p3 += e[i+3]*w[(size_t)(i+3)*100];
      }
      atomicAdd(&out[jj], (p0+p1)+(p2+p3));
    }
  } else {
    float p = 0.f;
    const float* e = emb + 6000;
    for(int i=t;i<6000;i+=256) p += e[i]*cfw[i];
    #pragma unroll
    for(int o=32;o>0;o>>=1) p += __shfl_down(p,o,64);
    __shared__ float red[4];
    if((t&63)==0) red[t>>6]=p;
    __syncthreads();
    if(t==0){
      float tot = red[0]+red[1]+red[2]+red[3];
      out[100] = tot + s0[0]*cfw[6000] + s1[0]*cfw[6001] + s2[0]*cfw[6002] + cfb[0];
    }
    if(t<100){
      atomicAdd(&out[t], afb[t] + s0[0]*afw[600000+t] + s1[0]*afw[600100+t] + s2[0]*afw[600200+t]);
    }
  }
}

extern "C" void kernel_launch(void* const* d_in, const int* in_sizes, int n_in,
                              void* d_out, int out_size, void* d_ws, size_t ws_size,
                              hipStream_t stream){
  const float* x   = (const float*)d_in[0];
  const int*   ei  = (const int*)d_in[1];
  const float* s0  = (const float*)d_in[2];
  const float* s1  = (const float*)d_in[3];
  const float* s2  = (const float*)d_in[4];
  const float* aw  = (const float*)d_in[5];
  const float* ab  = (const float*)d_in[6];
  const float* cw  = (const float*)d_in[7];
  const float* cb  = (const float*)d_in[8];
  const float* afw = (const float*)d_in[9];
  const float* afb = (const float*)d_in[10];
  const float* cfw = (const float*)d_in[11];
  const float* cfb = (const float*)d_in[12];
  float* out = (float*)d_out;

  float* Y   = (float*)d_ws;                       // [6][6000] reduced GEMM outputs
  float* emb = Y + 6*NN*CO;                        // [2][6000] tanh embeddings
  float* P   = emb + 2*NN*CO;                      // [6][G2][6000] split-K partials
  const size_t need = (size_t)(6*NN*CO + 2*NN*CO + (size_t)6*G2*NN*CO)*sizeof(float);
  const int partial = (ws_size >= need) ? 1 : 0;

  hipMemsetAsync(Y, 0, 6*NN*CO*sizeof(float), stream);

  if(partial){
    k_gemm<<<dim3(512), 256, 0, stream>>>(x, aw, cw, P, 1);
    k_reduce<<<dim3((6*NN*CO+255)/256, 8), 256, 0, stream>>>(P, Y);
  } else {
    k_gemm<<<dim3(512), 256, 0, stream>>>(x, aw, cw, Y, 0);
  }
  k_cheb<<<120, 128, 0, stream>>>(Y, ei, ab, cb, emb, out);
  k_fc<<<FCB+1, 256, 0, stream>>>(emb, afw, afb, cfw, cfb, s0, s1, s2, out);
}